// Round 16
// baseline (71.417 us; speedup 1.0000x reference)
//
#include <hip/hip_runtime.h>

#define DEVFN __device__ __forceinline__

constexpr int BNN = 64 * 64 * 64;              // 262144 per output tensor
constexpr float SCALE = 0.08838834764831845f;  // 1/sqrt(128)
constexpr float NSLOPE = 0.01f;

// ---- ws layout (floats) ---- (11.93 MB, proven)
constexpr int OFF_WPRET = 0;       // [64][128]
constexpr int OFF_CNT   = 8192;    // per-batch barrier counters (64 x u32; dead WQT slot)
constexpr int OFF_M     = 24576;   // [128][128]  M = Wq^T Wk
constexpr int OFF_WSET  = 40960;   // [128][128]
constexpr int OFF_WSAPT = 57344;   // [96][128]
constexpr int OFF_WAVT  = 69632;   // [128][128]
constexpr int OFF_WF1T  = 86016;   // [128][64]
constexpr int OFF_E     = 98304;    // [4096][128] e row-major
constexpr int OFF_Q     = 622592;   // [4096][128] f (P1 -> P34)
constexpr int OFF_ET    = 1146880;  // [B][128][64] e feature-major
constexpr int OFF_SET   = 1671168;  // [B][128][64] se feature-major
constexpr int OFF_HA    = 2195456;  // [B][64][64]
constexpr int OFF_HD    = 2719744;  // [B][64][64]

// ============ small helpers (functions, not macros) ============

DEVFN void fma4(float (&acc)[4], float a, const float4& bv) {
  acc[0] += a * bv.x; acc[1] += a * bv.y; acc[2] += a * bv.z; acc[3] += a * bv.w;
}
DEVFN void fma2(float (&acc)[2], float a, const float2& bv) {
  acc[0] += a * bv.x; acc[1] += a * bv.y;
}

// ============ staging: global (tight) -> LDS (padded pitch) ============

template<int NT>
DEVFN void st128(int tid, const float* __restrict__ src, float* __restrict__ Bs, int rows) {
  const int n4 = rows * 32;
  for (int idx = tid; idx < n4; idx += NT) {
    const int r = idx >> 5, c = idx & 31;
    *reinterpret_cast<float4*>(&Bs[r * 132 + c * 4]) =
        *reinterpret_cast<const float4*>(&src[r * 128 + c * 4]);
  }
}

template<int NT>
DEVFN void st64r(int tid, const float* __restrict__ src, float* __restrict__ Bs, int rows) {
  const int n4 = rows * 16;
  for (int idx = tid; idx < n4; idx += NT) {
    const int r = idx >> 4, c = idx & 15;
    *reinterpret_cast<float4*>(&Bs[r * 68 + c * 4]) =
        *reinterpret_cast<const float4*>(&src[r * 64 + c * 4]);
  }
}

// Coalesced feature-major writeout (512 thr): src LDS [16][132] -> dst global [128][64]
DEVFN void wrT(int tid, const float* __restrict__ S, float* __restrict__ dst, int rq) {
  const int fr = tid >> 2, a4 = tid & 3;
  float t[4];
#pragma unroll
  for (int i = 0; i < 4; ++i) t[i] = S[(a4 * 4 + i) * 132 + fr];
  float4 v; v.x = t[0]; v.y = t[1]; v.z = t[2]; v.w = t[3];
  *reinterpret_cast<float4*>(&dst[fr * 64 + rq * 16 + a4 * 4]) = v;
}

// ============ GEMM cores: 512 thr, 16 rows x 128 cols, 1 row x 4 cols/thread ============

DEVFN void g1(int tid, const float* __restrict__ A, int lda,
              const float* __restrict__ Bs, int K, float (&acc)[4]) {
  const int c0 = (tid & 31) * 4, rg = tid >> 5;
  const float* __restrict__ Ar = A + rg * lda;
#pragma unroll 4
  for (int k4 = 0; k4 < K; k4 += 4) {
    const float4 a4 = *reinterpret_cast<const float4*>(&Ar[k4]);
    const float4 b0 = *reinterpret_cast<const float4*>(&Bs[(k4 + 0) * 132 + c0]);
    const float4 b1 = *reinterpret_cast<const float4*>(&Bs[(k4 + 1) * 132 + c0]);
    const float4 b2 = *reinterpret_cast<const float4*>(&Bs[(k4 + 2) * 132 + c0]);
    const float4 b3 = *reinterpret_cast<const float4*>(&Bs[(k4 + 3) * 132 + c0]);
    fma4(acc, a4.x, b0); fma4(acc, a4.y, b1); fma4(acc, a4.z, b2); fma4(acc, a4.w, b3);
  }
}

DEVFN void g2A(int tid, const float* __restrict__ A0, const float* __restrict__ A1,
               int lda, const float* __restrict__ Bs, int K,
               float (&a0)[4], float (&a1)[4]) {
  const int c0 = (tid & 31) * 4, rg = tid >> 5;
  const float* __restrict__ X = A0 + rg * lda;
  const float* __restrict__ Y = A1 + rg * lda;
#pragma unroll 2
  for (int k4 = 0; k4 < K; k4 += 4) {
    const float4 x4 = *reinterpret_cast<const float4*>(&X[k4]);
    const float4 y4 = *reinterpret_cast<const float4*>(&Y[k4]);
    const float4 b0 = *reinterpret_cast<const float4*>(&Bs[(k4 + 0) * 132 + c0]);
    const float4 b1 = *reinterpret_cast<const float4*>(&Bs[(k4 + 1) * 132 + c0]);
    const float4 b2 = *reinterpret_cast<const float4*>(&Bs[(k4 + 2) * 132 + c0]);
    const float4 b3 = *reinterpret_cast<const float4*>(&Bs[(k4 + 3) * 132 + c0]);
    fma4(a0, x4.x, b0); fma4(a1, y4.x, b0);
    fma4(a0, x4.y, b1); fma4(a1, y4.y, b1);
    fma4(a0, x4.z, b2); fma4(a1, y4.z, b2);
    fma4(a0, x4.w, b3); fma4(a1, y4.w, b3);
  }
}

// 64-col variants: 1 row x 2 cols, B pitch 68 float2
DEVFN void gH(int tid, const float* __restrict__ A, int lda,
              const float* __restrict__ Bs, int K, float (&acc)[2]) {
  const int c0 = (tid & 31) * 2, rg = tid >> 5;
  const float* __restrict__ Ar = A + rg * lda;
#pragma unroll 4
  for (int k4 = 0; k4 < K; k4 += 4) {
    const float4 a4 = *reinterpret_cast<const float4*>(&Ar[k4]);
    const float2 b0 = *reinterpret_cast<const float2*>(&Bs[(k4 + 0) * 68 + c0]);
    const float2 b1 = *reinterpret_cast<const float2*>(&Bs[(k4 + 1) * 68 + c0]);
    const float2 b2 = *reinterpret_cast<const float2*>(&Bs[(k4 + 2) * 68 + c0]);
    const float2 b3 = *reinterpret_cast<const float2*>(&Bs[(k4 + 3) * 68 + c0]);
    fma2(acc, a4.x, b0); fma2(acc, a4.y, b1); fma2(acc, a4.z, b2); fma2(acc, a4.w, b3);
  }
}

DEVFN void gH2(int tid, const float* __restrict__ A0, const float* __restrict__ A1,
               int lda, const float* __restrict__ Bs, int K,
               float (&a0)[2], float (&a1)[2]) {
  const int c0 = (tid & 31) * 2, rg = tid >> 5;
  const float* __restrict__ X = A0 + rg * lda;
  const float* __restrict__ Y = A1 + rg * lda;
#pragma unroll 2
  for (int k4 = 0; k4 < K; k4 += 4) {
    const float4 x4 = *reinterpret_cast<const float4*>(&X[k4]);
    const float4 y4 = *reinterpret_cast<const float4*>(&Y[k4]);
    const float2 b0 = *reinterpret_cast<const float2*>(&Bs[(k4 + 0) * 68 + c0]);
    const float2 b1 = *reinterpret_cast<const float2*>(&Bs[(k4 + 1) * 68 + c0]);
    const float2 b2 = *reinterpret_cast<const float2*>(&Bs[(k4 + 2) * 68 + c0]);
    const float2 b3 = *reinterpret_cast<const float2*>(&Bs[(k4 + 3) * 68 + c0]);
    fma2(a0, x4.x, b0); fma2(a1, y4.x, b0);
    fma2(a0, x4.y, b1); fma2(a1, y4.y, b1);
    fma2(a0, x4.z, b2); fma2(a1, y4.z, b2);
    fma2(a0, x4.w, b3); fma2(a1, y4.w, b3);
  }
}

template<bool ACT, bool HASB>
DEVFN void epi(int tid, const float (&acc)[4], float* __restrict__ O, int ldo,
               const float* __restrict__ bias) {
  const int c0 = (tid & 31) * 4, rg = tid >> 5;
  float t[4];
#pragma unroll
  for (int i = 0; i < 4; ++i) {
    float x = acc[i];
    if constexpr (HASB) x += bias[c0 + i];
    if constexpr (ACT) x = (x > 0.f) ? x : NSLOPE * x;
    t[i] = x;
  }
  float4 v; v.x = t[0]; v.y = t[1]; v.z = t[2]; v.w = t[3];
  *reinterpret_cast<float4*>(&O[rg * ldo + c0]) = v;
}

// ============ score (K=128 in one pass) + softmax: 512 thr, 16 rows ============

DEVFN void score_full(int tid, const float* __restrict__ Qs,
                      const float* __restrict__ Ks, float (&acc)[2]) {
  const int j = tid & 63, iw = tid >> 6;
#pragma unroll 2
  for (int kt = 0; kt < 128; kt += 8) {
    float qv[2][8];
#pragma unroll
    for (int r = 0; r < 2; ++r) {
      *reinterpret_cast<float4*>(&qv[r][0]) =
          *reinterpret_cast<const float4*>(&Qs[(iw * 2 + r) * 132 + kt]);
      *reinterpret_cast<float4*>(&qv[r][4]) =
          *reinterpret_cast<const float4*>(&Qs[(iw * 2 + r) * 132 + kt + 4]);
    }
#pragma unroll
    for (int kk = 0; kk < 8; ++kk) {
      const float kv = Ks[(kt + kk) * 68 + j];
      acc[0] += qv[0][kk] * kv;
      acc[1] += qv[1][kk] * kv;
    }
  }
}

DEVFN void softmax_write(int tid, float (&acc)[2], float* __restrict__ Wp,
                         float* __restrict__ gout) {
  const int j = tid & 63, iw = tid >> 6;
#pragma unroll
  for (int r = 0; r < 2; ++r) {
    float v = acc[r] * SCALE;
    float m = v;
#pragma unroll
    for (int off = 32; off > 0; off >>= 1) m = fmaxf(m, __shfl_xor(m, off, 64));
    const float p = __expf(v - m);
    float s = p;
#pragma unroll
    for (int off = 32; off > 0; off >>= 1) s += __shfl_xor(s, off, 64);
    const float w = p / s;
    Wp[(iw * 2 + r) * 68 + j] = w;
    gout[(iw * 2 + r) * 64 + j] = w;
  }
}

// ============ per-batch group barrier: release/acquire atomics, NO threadfence ============
// All 256 blocks co-resident (grid 256 = 1 block/CU, LDS well under 160KB) -> no deadlock.
DEVFN void groupbar(unsigned* __restrict__ cnt, int tid) {
  __syncthreads();
  if (tid == 0) {
    __hip_atomic_fetch_add(cnt, 1u, __ATOMIC_RELEASE, __HIP_MEMORY_SCOPE_AGENT);
    while (__hip_atomic_load(cnt, __ATOMIC_ACQUIRE, __HIP_MEMORY_SCOPE_AGENT) < 4u) {
      __builtin_amdgcn_s_sleep(2);
    }
  }
  __syncthreads();
}

// ===================== kernel 1: weight transposes + M = Wq^T Wk =====================

__global__ __launch_bounds__(512) void WPREP(const float* __restrict__ Wpre,
                                             const float* __restrict__ Wq,
                                             const float* __restrict__ Wkey,
                                             const float* __restrict__ Wse,
                                             const float* __restrict__ Wsap,
                                             const float* __restrict__ Wav,
                                             const float* __restrict__ Wf1,
                                             float* __restrict__ ws) {
  __shared__ float As[16 * 132];
  __shared__ float Bs[64 * 132];
  const int tid = threadIdx.x, bid = blockIdx.x;
  if (bid < 120) {
    const int gt = bid * 512 + tid;
    if (gt < 8192) {                       // Wpre [128][64] -> WPRET [64][128]
      const int c = gt >> 6, k = gt & 63;
      ws[OFF_WPRET + k * 128 + c] = Wpre[gt];
    } else if (gt < 24576) {               // Wse -> WSET
      const int i = gt - 8192, c = i >> 7, k = i & 127;
      ws[OFF_WSET + k * 128 + c] = Wse[i];
    } else if (gt < 36864) {               // Wsap [128][96] -> WSAPT [96][128]
      const int i = gt - 24576, c = i / 96, k = i - c * 96;
      ws[OFF_WSAPT + k * 128 + c] = Wsap[i];
    } else if (gt < 53248) {               // Wav -> WAVT
      const int i = gt - 36864, c = i >> 7, k = i & 127;
      ws[OFF_WAVT + k * 128 + c] = Wav[i];
    } else if (gt < 61440) {               // Wf1 [64][128] -> WF1T [128][64]
      const int i = gt - 53248, c = i >> 7, k = i & 127;
      ws[OFF_WF1T + k * 64 + c] = Wf1[i];
    }
  } else {
    const int r0 = (bid - 120) * 16;
    for (int idx = tid; idx < 2048; idx += 512) {
      const int r = idx & 15, o = idx >> 4;
      As[r * 132 + o] = Wq[o * 128 + r0 + r];
    }
    const int c0 = (tid & 31) * 4, rg = tid >> 5;
    float acc[4] = {};
    for (int h = 0; h < 2; ++h) {
      __syncthreads();
      st128<512>(tid, Wkey + h * 8192, Bs, 64);
      __syncthreads();
#pragma unroll 8
      for (int k = 0; k < 64; ++k) {
        const float4 bv = *reinterpret_cast<const float4*>(&Bs[k * 132 + c0]);
        fma4(acc, As[rg * 132 + h * 64 + k], bv);
      }
    }
    float4 v; v.x = acc[0]; v.y = acc[1]; v.z = acc[2]; v.w = acc[3];
    *reinterpret_cast<float4*>(&ws[OFF_M + (r0 + rg) * 128 + c0]) = v;
  }
}

// P1: grid 256 (XCD-swizzled), 512 thr, 16 rows. (unchanged from R15)
__global__ __launch_bounds__(512) void P1(const float* __restrict__ states,
                                          const float* __restrict__ policies,
                                          const float* __restrict__ actions,
                                          const float* __restrict__ b_sap,
                                          const float* __restrict__ b_se_pre,
                                          float* __restrict__ ws) {
  __shared__ float S[16 * 68];
  __shared__ float Aa[16 * 36], Ap[16 * 36];
  __shared__ float Ea[16 * 132];   // E_act -> AVs
  __shared__ float Ep[16 * 132], Dd[16 * 132], Er[16 * 132];
  __shared__ float Bs[8704];
  const int tid = threadIdx.x;
  const int wid = ((blockIdx.x & 7) << 5) | (blockIdx.x >> 3);
  const int b = wid >> 2, rq = wid & 3;
  const int r0g = b * 64 + rq * 16;

  for (int idx = tid; idx < 1024; idx += 512) {
    const int r = idx >> 6, c = idx & 63;
    S[r * 68 + c] = states[(r0g + r) * 64 + c];
  }
  {
    const int r = tid >> 5, c = tid & 31;
    Aa[r * 36 + c] = actions[(r0g + r) * 32 + c];
    Ap[r * 36 + c] = policies[(r0g + r) * 32 + c];
  }
  st128<512>(tid, ws + OFF_WSAPT, Bs, 64);
  __syncthreads();
  float cm[4] = {};
  g1(tid, S, 68, Bs, 64, cm);
  __syncthreads();
  st128<512>(tid, ws + OFF_WSAPT + 8192, Bs, 32);
  __syncthreads();
  float aa[4] = {cm[0], cm[1], cm[2], cm[3]};
  float ap[4] = {cm[0], cm[1], cm[2], cm[3]};
  g2A(tid, Aa, Ap, 36, Bs, 32, aa, ap);
  epi<true, true>(tid, aa, Ea, 132, b_sap);
  epi<true, true>(tid, ap, Ep, 132, b_sap);
  __syncthreads();
  for (int idx = tid; idx < 2048; idx += 512) {
    const int r = idx >> 7, c = idx & 127;
    Ep[r * 132 + c] -= Ea[r * 132 + c];
  }
  __syncthreads();
  st128<512>(tid, ws + OFF_WAVT, Bs, 64);
  __syncthreads();
  float av[4] = {}, dl[4] = {};
  g2A(tid, Ea, Ep, 132, Bs, 64, av, dl);
  __syncthreads();
  st128<512>(tid, ws + OFF_WAVT + 8192, Bs, 64);
  __syncthreads();
  g2A(tid, Ea + 64, Ep + 64, 132, Bs, 64, av, dl);
  __syncthreads();
  epi<false, false>(tid, av, Ea, 132, nullptr);  // Ea := AVs
  epi<false, false>(tid, dl, Dd, 132, nullptr);
  __syncthreads();
  st64r<512>(tid, ws + OFF_WF1T, Bs, 128);
  __syncthreads();
  float ah[2] = {}, aha[2] = {};
  gH2(tid, Dd, Ea, 132, Bs, 64, ah, aha);
  gH2(tid, Dd + 64, Ea + 64, 132, Bs + 64 * 68, 64, ah, aha);
  {
    const int c0 = (tid & 31) * 2, rg = tid >> 5;
    float2 vh; vh.x = ah[0]; vh.y = ah[1];
    float2 va; va.x = aha[0]; va.y = aha[1];
    *reinterpret_cast<float2*>(&ws[OFF_HD + (r0g + rg) * 64 + c0]) = vh;
    *reinterpret_cast<float2*>(&ws[OFF_HA + (r0g + rg) * 64 + c0]) = va;
  }
  __syncthreads();
  st128<512>(tid, ws + OFF_WPRET, Bs, 64);
  __syncthreads();
  {
    float ae[4] = {};
    g1(tid, S, 68, Bs, 64, ae);
    const int c0 = (tid & 31) * 4, rg = tid >> 5;
    float t[4];
#pragma unroll
    for (int i = 0; i < 4; ++i) {
      float x = ae[i] + b_se_pre[c0 + i];
      t[i] = (x > 0.f) ? x : NSLOPE * x;
    }
    float4 v; v.x = t[0]; v.y = t[1]; v.z = t[2]; v.w = t[3];
    *reinterpret_cast<float4*>(&Er[rg * 132 + c0]) = v;
    *reinterpret_cast<float4*>(&ws[OFF_E + (r0g + rg) * 128 + c0]) = v;
  }
  __syncthreads();
  wrT(tid, Er, ws + OFF_ET + b * 8192, rq);
  st128<512>(tid, ws + OFF_M, Bs, 64);
  __syncthreads();
  float af[4] = {};
  g1(tid, Er, 132, Bs, 64, af);
  __syncthreads();
  st128<512>(tid, ws + OFF_M + 8192, Bs, 64);
  __syncthreads();
  g1(tid, Er + 64, 132, Bs, 64, af);
  epi<false, false>(tid, af, ws + OFF_Q + r0g * 128, 128, nullptr);
}

// P34: merged P3+P4 with one per-batch group barrier. grid 256 (swizzled), 512 thr.
__global__ __launch_bounds__(512) void P34(const float* __restrict__ b_se,
                                           const float* __restrict__ Wf2g,
                                           float* __restrict__ ws,
                                           float* __restrict__ out) {
  __shared__ float Qs[16 * 132];   // f -> f2 (never leaves LDS)
  __shared__ float Bs[8704];
  __shared__ float Wp[16 * 68];
  __shared__ float AV[16 * 132];
  __shared__ float SEr[16 * 132];
  __shared__ float Hd[64 * 69];
  __shared__ float Hb[16 * 66];
  __shared__ float Wf2s[64];
  const int tid = threadIdx.x;
  const int wid = ((blockIdx.x & 7) << 5) | (blockIdx.x >> 3);
  const int b = wid >> 2, rq = wid & 3;
  const int r0g = b * 64 + rq * 16;
  unsigned* cnt = (unsigned*)(ws + OFF_CNT) + b;

  // early loads (only depend on P1): f, Hd, Wf2
  {
    const int r = tid >> 5, c = tid & 31;
    *reinterpret_cast<float4*>(&Qs[r * 132 + c * 4]) =
        *reinterpret_cast<const float4*>(&ws[OFF_Q + (r0g + r) * 128 + c * 4]);
  }
  for (int idx = tid; idx < 4096; idx += 512)
    Hd[(idx >> 6) * 69 + (idx & 63)] = ws[OFF_HD + b * 4096 + idx];
  if (tid < 64) Wf2s[tid] = Wf2g[tid];
  st64r<512>(tid, ws + OFF_ET + b * 8192, Bs, 128);
  __syncthreads();
  // score1 + softmax -> w_pre
  float sc[2] = {};
  score_full(tid, Qs, Bs, sc);
  softmax_write(tid, sc, Wp, out + BNN + b * 4096 + rq * 1024);
  __syncthreads();
  // av_pre = w_pre @ e[b] (K=64)
  st128<512>(tid, ws + OFF_E + b * 8192, Bs, 64);
  __syncthreads();
  {
    float a[4] = {};
    g1(tid, Wp, 68, Bs, 64, a);
    epi<false, false>(tid, a, AV, 132, nullptr);
  }
  __syncthreads();
  // se = lrelu(av_pre @ Wse^T + b_se) (K=128)
  st128<512>(tid, ws + OFF_WSET, Bs, 64);
  __syncthreads();
  float as[4] = {};
  g1(tid, AV, 132, Bs, 64, as);
  __syncthreads();
  st128<512>(tid, ws + OFF_WSET + 8192, Bs, 64);
  __syncthreads();
  g1(tid, AV + 64, 132, Bs, 64, as);
  {
    const int c0 = (tid & 31) * 4, rg = tid >> 5;
    float t[4];
#pragma unroll
    for (int i = 0; i < 4; ++i) {
      float x = as[i] + b_se[c0 + i];
      t[i] = (x > 0.f) ? x : NSLOPE * x;
    }
    float4 v; v.x = t[0]; v.y = t[1]; v.z = t[2]; v.w = t[3];
    *reinterpret_cast<float4*>(&SEr[rg * 132 + c0]) = v;
  }
  __syncthreads();
  wrT(tid, SEr, ws + OFF_SET + b * 8192, rq);   // visible to siblings after groupbar
  st128<512>(tid, ws + OFF_M, Bs, 64);
  __syncthreads();
  // f2 = se @ M (K=128) -> Qs (LDS only)
  float af[4] = {};
  g1(tid, SEr, 132, Bs, 64, af);
  __syncthreads();
  st128<512>(tid, ws + OFF_M + 8192, Bs, 64);
  __syncthreads();
  g1(tid, SEr + 64, 132, Bs, 64, af);
  epi<false, false>(tid, af, Qs, 132, nullptr);

  groupbar(cnt, tid);  // wait for all 4 sibling blocks' SET writes

  // score2 + softmax -> w
  st64r<512>(tid, ws + OFF_SET + b * 8192, Bs, 128);
  __syncthreads();
  float sc2[2] = {};
  score_full(tid, Qs, Bs, sc2);
  softmax_write(tid, sc2, Wp, out + 2 * BNN + b * 4096 + rq * 1024);
  __syncthreads();
  // h_base = w @ ha[b] (K=64)
  st64r<512>(tid, ws + OFF_HA + b * 4096, Bs, 64);
  __syncthreads();
  float ah[2] = {};
  gH(tid, Wp, 68, Bs, 64, ah);
  {
    const int c0 = (tid & 31) * 2, rg = tid >> 5;
    float2 v; v.x = ah[0]; v.y = ah[1];
    *reinterpret_cast<float2*>(&Hb[rg * 66 + c0]) = v;
  }
  __syncthreads();
  // head: value[i][j] = sum_f lrelu(Hb[i,f] + w[i,j]*Hd[j,f]) * Wf2[f]
  const int j = tid & 63, iw = tid >> 6;
  float wv[2], a2[2] = {0.f, 0.f};
#pragma unroll
  for (int r = 0; r < 2; ++r) wv[r] = Wp[(iw * 2 + r) * 68 + j];
  for (int f = 0; f < 64; ++f) {
    const float hdv = Hd[j * 69 + f];
    const float wf = Wf2s[f];
#pragma unroll
    for (int r = 0; r < 2; ++r) {
      float t = Hb[(iw * 2 + r) * 66 + f] + wv[r] * hdv;
      t = (t > 0.f) ? t : NSLOPE * t;
      a2[r] += t * wf;
    }
  }
#pragma unroll
  for (int r = 0; r < 2; ++r)
    out[(r0g + iw * 2 + r) * 64 + j] = a2[r];
}

extern "C" void kernel_launch(void* const* d_in, const int* in_sizes, int n_in,
                              void* d_out, int out_size, void* d_ws, size_t ws_size,
                              hipStream_t stream) {
  const float* states   = (const float*)d_in[0];
  const float* policies = (const float*)d_in[1];
  const float* actions  = (const float*)d_in[2];
  const float* W_se_pre = (const float*)d_in[3];
  const float* b_se_pre = (const float*)d_in[4];
  const float* W_key    = (const float*)d_in[5];
  const float* W_query  = (const float*)d_in[6];
  const float* W_se     = (const float*)d_in[7];
  const float* b_se     = (const float*)d_in[8];
  const float* W_sap    = (const float*)d_in[9];
  const float* b_sap    = (const float*)d_in[10];
  const float* W_av     = (const float*)d_in[11];
  const float* W_f1     = (const float*)d_in[12];
  const float* W_f2     = (const float*)d_in[13];
  float* out = (float*)d_out;
  float* ws  = (float*)d_ws;

  hipMemsetAsync(ws + OFF_CNT, 0, 64 * sizeof(unsigned), stream);
  WPREP<<<dim3(128), dim3(512), 0, stream>>>(
      W_se_pre, W_query, W_key, W_se, W_sap, W_av, W_f1, ws);
  P1<<<dim3(256), dim3(512), 0, stream>>>(states, policies, actions, b_sap, b_se_pre, ws);
  P34<<<dim3(256), dim3(512), 0, stream>>>(b_se, W_f2, ws, out);
}

// Round 17
// 62.231 us; speedup vs baseline: 1.1476x; 1.1476x over previous
//
#include <hip/hip_runtime.h>

#define DEVFN __device__ __forceinline__

constexpr int BNN = 64 * 64 * 64;              // 262144 per output tensor
constexpr float SCALE = 0.08838834764831845f;  // 1/sqrt(128)
constexpr float NSLOPE = 0.01f;

// ---- ws layout (floats) ---- (11.93 MB, proven)
constexpr int OFF_WPRET = 0;       // [64][128]
constexpr int OFF_M     = 24576;   // [128][128]  M = Wq^T Wk
constexpr int OFF_WSET  = 40960;   // [128][128]
constexpr int OFF_WSAPT = 57344;   // [96][128]
constexpr int OFF_WAVT  = 69632;   // [128][128]
constexpr int OFF_WF1T  = 86016;   // [128][64]
constexpr int OFF_E     = 98304;    // [4096][128] e row-major
constexpr int OFF_Q     = 622592;   // [4096][128] f then f2 (same-row aliasing, safe)
constexpr int OFF_ET    = 1146880;  // [B][128][64] e feature-major
constexpr int OFF_SET   = 1671168;  // [B][128][64] se feature-major
constexpr int OFF_HA    = 2195456;  // [B][64][64]
constexpr int OFF_HD    = 2719744;  // [B][64][64]

// ============ small helpers (functions, not macros) ============

DEVFN void fma4(float (&acc)[4], float a, const float4& bv) {
  acc[0] += a * bv.x; acc[1] += a * bv.y; acc[2] += a * bv.z; acc[3] += a * bv.w;
}
DEVFN void fma2(float (&acc)[2], float a, const float2& bv) {
  acc[0] += a * bv.x; acc[1] += a * bv.y;
}

// ============ staging: global (tight) -> LDS (padded pitch) ============

template<int NT>
DEVFN void st128(int tid, const float* __restrict__ src, float* __restrict__ Bs, int rows) {
  const int n4 = rows * 32;
  for (int idx = tid; idx < n4; idx += NT) {
    const int r = idx >> 5, c = idx & 31;
    *reinterpret_cast<float4*>(&Bs[r * 132 + c * 4]) =
        *reinterpret_cast<const float4*>(&src[r * 128 + c * 4]);
  }
}

template<int NT>
DEVFN void st64r(int tid, const float* __restrict__ src, float* __restrict__ Bs, int rows) {
  const int n4 = rows * 16;
  for (int idx = tid; idx < n4; idx += NT) {
    const int r = idx >> 4, c = idx & 15;
    *reinterpret_cast<float4*>(&Bs[r * 68 + c * 4]) =
        *reinterpret_cast<const float4*>(&src[r * 64 + c * 4]);
  }
}

// Coalesced feature-major writeout (512 thr): src LDS [16][132] -> dst global [128][64]
DEVFN void wrT(int tid, const float* __restrict__ S, float* __restrict__ dst, int rq) {
  const int fr = tid >> 2, a4 = tid & 3;
  float t[4];
#pragma unroll
  for (int i = 0; i < 4; ++i) t[i] = S[(a4 * 4 + i) * 132 + fr];
  float4 v; v.x = t[0]; v.y = t[1]; v.z = t[2]; v.w = t[3];
  *reinterpret_cast<float4*>(&dst[fr * 64 + rq * 16 + a4 * 4]) = v;
}

// ============ GEMM cores: 512 thr, 16 rows x 128 cols, 1 row x 4 cols/thread ============
// A loaded as float4 per 4 k's (rows are 16B-aligned: all pitches divisible by 4).

DEVFN void g1(int tid, const float* __restrict__ A, int lda,
              const float* __restrict__ Bs, int K, float (&acc)[4]) {
  const int c0 = (tid & 31) * 4, rg = tid >> 5;
  const float* __restrict__ Ar = A + rg * lda;
#pragma unroll 4
  for (int k4 = 0; k4 < K; k4 += 4) {
    const float4 a4 = *reinterpret_cast<const float4*>(&Ar[k4]);
    const float4 b0 = *reinterpret_cast<const float4*>(&Bs[(k4 + 0) * 132 + c0]);
    const float4 b1 = *reinterpret_cast<const float4*>(&Bs[(k4 + 1) * 132 + c0]);
    const float4 b2 = *reinterpret_cast<const float4*>(&Bs[(k4 + 2) * 132 + c0]);
    const float4 b3 = *reinterpret_cast<const float4*>(&Bs[(k4 + 3) * 132 + c0]);
    fma4(acc, a4.x, b0); fma4(acc, a4.y, b1); fma4(acc, a4.z, b2); fma4(acc, a4.w, b3);
  }
}

DEVFN void g2A(int tid, const float* __restrict__ A0, const float* __restrict__ A1,
               int lda, const float* __restrict__ Bs, int K,
               float (&a0)[4], float (&a1)[4]) {
  const int c0 = (tid & 31) * 4, rg = tid >> 5;
  const float* __restrict__ X = A0 + rg * lda;
  const float* __restrict__ Y = A1 + rg * lda;
#pragma unroll 2
  for (int k4 = 0; k4 < K; k4 += 4) {
    const float4 x4 = *reinterpret_cast<const float4*>(&X[k4]);
    const float4 y4 = *reinterpret_cast<const float4*>(&Y[k4]);
    const float4 b0 = *reinterpret_cast<const float4*>(&Bs[(k4 + 0) * 132 + c0]);
    const float4 b1 = *reinterpret_cast<const float4*>(&Bs[(k4 + 1) * 132 + c0]);
    const float4 b2 = *reinterpret_cast<const float4*>(&Bs[(k4 + 2) * 132 + c0]);
    const float4 b3 = *reinterpret_cast<const float4*>(&Bs[(k4 + 3) * 132 + c0]);
    fma4(a0, x4.x, b0); fma4(a1, y4.x, b0);
    fma4(a0, x4.y, b1); fma4(a1, y4.y, b1);
    fma4(a0, x4.z, b2); fma4(a1, y4.z, b2);
    fma4(a0, x4.w, b3); fma4(a1, y4.w, b3);
  }
}

// 64-col variants: 1 row x 2 cols, B pitch 68 float2
DEVFN void gH(int tid, const float* __restrict__ A, int lda,
              const float* __restrict__ Bs, int K, float (&acc)[2]) {
  const int c0 = (tid & 31) * 2, rg = tid >> 5;
  const float* __restrict__ Ar = A + rg * lda;
#pragma unroll 4
  for (int k4 = 0; k4 < K; k4 += 4) {
    const float4 a4 = *reinterpret_cast<const float4*>(&Ar[k4]);
    const float2 b0 = *reinterpret_cast<const float2*>(&Bs[(k4 + 0) * 68 + c0]);
    const float2 b1 = *reinterpret_cast<const float2*>(&Bs[(k4 + 1) * 68 + c0]);
    const float2 b2 = *reinterpret_cast<const float2*>(&Bs[(k4 + 2) * 68 + c0]);
    const float2 b3 = *reinterpret_cast<const float2*>(&Bs[(k4 + 3) * 68 + c0]);
    fma2(acc, a4.x, b0); fma2(acc, a4.y, b1); fma2(acc, a4.z, b2); fma2(acc, a4.w, b3);
  }
}

DEVFN void gH2(int tid, const float* __restrict__ A0, const float* __restrict__ A1,
               int lda, const float* __restrict__ Bs, int K,
               float (&a0)[2], float (&a1)[2]) {
  const int c0 = (tid & 31) * 2, rg = tid >> 5;
  const float* __restrict__ X = A0 + rg * lda;
  const float* __restrict__ Y = A1 + rg * lda;
#pragma unroll 2
  for (int k4 = 0; k4 < K; k4 += 4) {
    const float4 x4 = *reinterpret_cast<const float4*>(&X[k4]);
    const float4 y4 = *reinterpret_cast<const float4*>(&Y[k4]);
    const float2 b0 = *reinterpret_cast<const float2*>(&Bs[(k4 + 0) * 68 + c0]);
    const float2 b1 = *reinterpret_cast<const float2*>(&Bs[(k4 + 1) * 68 + c0]);
    const float2 b2 = *reinterpret_cast<const float2*>(&Bs[(k4 + 2) * 68 + c0]);
    const float2 b3 = *reinterpret_cast<const float2*>(&Bs[(k4 + 3) * 68 + c0]);
    fma2(a0, x4.x, b0); fma2(a1, y4.x, b0);
    fma2(a0, x4.y, b1); fma2(a1, y4.y, b1);
    fma2(a0, x4.z, b2); fma2(a1, y4.z, b2);
    fma2(a0, x4.w, b3); fma2(a1, y4.w, b3);
  }
}

template<bool ACT, bool HASB>
DEVFN void epi(int tid, const float (&acc)[4], float* __restrict__ O, int ldo,
               const float* __restrict__ bias) {
  const int c0 = (tid & 31) * 4, rg = tid >> 5;
  float t[4];
#pragma unroll
  for (int i = 0; i < 4; ++i) {
    float x = acc[i];
    if constexpr (HASB) x += bias[c0 + i];
    if constexpr (ACT) x = (x > 0.f) ? x : NSLOPE * x;
    t[i] = x;
  }
  float4 v; v.x = t[0]; v.y = t[1]; v.z = t[2]; v.w = t[3];
  *reinterpret_cast<float4*>(&O[rg * ldo + c0]) = v;
}

// ============ score (K=128 in one pass) + softmax: 512 thr, 16 rows ============

DEVFN void score_full(int tid, const float* __restrict__ Qs,
                      const float* __restrict__ Ks, float (&acc)[2]) {
  const int j = tid & 63, iw = tid >> 6;
#pragma unroll 2
  for (int kt = 0; kt < 128; kt += 8) {
    float qv[2][8];
#pragma unroll
    for (int r = 0; r < 2; ++r) {
      *reinterpret_cast<float4*>(&qv[r][0]) =
          *reinterpret_cast<const float4*>(&Qs[(iw * 2 + r) * 132 + kt]);
      *reinterpret_cast<float4*>(&qv[r][4]) =
          *reinterpret_cast<const float4*>(&Qs[(iw * 2 + r) * 132 + kt + 4]);
    }
#pragma unroll
    for (int kk = 0; kk < 8; ++kk) {
      const float kv = Ks[(kt + kk) * 68 + j];
      acc[0] += qv[0][kk] * kv;
      acc[1] += qv[1][kk] * kv;
    }
  }
}

DEVFN void softmax_write(int tid, float (&acc)[2], float* __restrict__ Wp,
                         float* __restrict__ gout) {
  const int j = tid & 63, iw = tid >> 6;
#pragma unroll
  for (int r = 0; r < 2; ++r) {
    float v = acc[r] * SCALE;
    float m = v;
#pragma unroll
    for (int off = 32; off > 0; off >>= 1) m = fmaxf(m, __shfl_xor(m, off, 64));
    const float p = __expf(v - m);
    float s = p;
#pragma unroll
    for (int off = 32; off > 0; off >>= 1) s += __shfl_xor(s, off, 64);
    const float w = p / s;
    Wp[(iw * 2 + r) * 68 + j] = w;
    gout[(iw * 2 + r) * 64 + j] = w;
  }
}

// ===================== kernel 1: weight transposes + M = Wq^T Wk =====================

__global__ __launch_bounds__(512) void WPREP(const float* __restrict__ Wpre,
                                             const float* __restrict__ Wq,
                                             const float* __restrict__ Wkey,
                                             const float* __restrict__ Wse,
                                             const float* __restrict__ Wsap,
                                             const float* __restrict__ Wav,
                                             const float* __restrict__ Wf1,
                                             float* __restrict__ ws) {
  __shared__ float As[16 * 132];
  __shared__ float Bs[64 * 132];
  const int tid = threadIdx.x, bid = blockIdx.x;
  if (bid < 120) {
    const int gt = bid * 512 + tid;
    if (gt < 8192) {                       // Wpre [128][64] -> WPRET [64][128]
      const int c = gt >> 6, k = gt & 63;
      ws[OFF_WPRET + k * 128 + c] = Wpre[gt];
    } else if (gt < 24576) {               // Wse -> WSET
      const int i = gt - 8192, c = i >> 7, k = i & 127;
      ws[OFF_WSET + k * 128 + c] = Wse[i];
    } else if (gt < 36864) {               // Wsap [128][96] -> WSAPT [96][128]
      const int i = gt - 24576, c = i / 96, k = i - c * 96;
      ws[OFF_WSAPT + k * 128 + c] = Wsap[i];
    } else if (gt < 53248) {               // Wav -> WAVT
      const int i = gt - 36864, c = i >> 7, k = i & 127;
      ws[OFF_WAVT + k * 128 + c] = Wav[i];
    } else if (gt < 61440) {               // Wf1 [64][128] -> WF1T [128][64]
      const int i = gt - 53248, c = i >> 7, k = i & 127;
      ws[OFF_WF1T + k * 64 + c] = Wf1[i];
    }
  } else {
    const int r0 = (bid - 120) * 16;
    for (int idx = tid; idx < 2048; idx += 512) {
      const int r = idx & 15, o = idx >> 4;
      As[r * 132 + o] = Wq[o * 128 + r0 + r];
    }
    const int c0 = (tid & 31) * 4, rg = tid >> 5;
    float acc[4] = {};
    for (int h = 0; h < 2; ++h) {
      __syncthreads();
      st128<512>(tid, Wkey + h * 8192, Bs, 64);
      __syncthreads();
#pragma unroll 8
      for (int k = 0; k < 64; ++k) {
        const float4 bv = *reinterpret_cast<const float4*>(&Bs[k * 132 + c0]);
        fma4(acc, As[rg * 132 + h * 64 + k], bv);
      }
    }
    float4 v; v.x = acc[0]; v.y = acc[1]; v.z = acc[2]; v.w = acc[3];
    *reinterpret_cast<float4*>(&ws[OFF_M + (r0 + rg) * 128 + c0]) = v;
  }
}

// P1: grid 256 (XCD-swizzled), 512 thr, 16 rows.
__global__ __launch_bounds__(512) void P1(const float* __restrict__ states,
                                          const float* __restrict__ policies,
                                          const float* __restrict__ actions,
                                          const float* __restrict__ b_sap,
                                          const float* __restrict__ b_se_pre,
                                          float* __restrict__ ws) {
  __shared__ float S[16 * 68];
  __shared__ float Aa[16 * 36], Ap[16 * 36];
  __shared__ float Ea[16 * 132];   // E_act -> AVs
  __shared__ float Ep[16 * 132], Dd[16 * 132], Er[16 * 132];
  __shared__ float Bs[8704];
  const int tid = threadIdx.x;
  const int wid = ((blockIdx.x & 7) << 5) | (blockIdx.x >> 3);
  const int b = wid >> 2, rq = wid & 3;
  const int r0g = b * 64 + rq * 16;

  for (int idx = tid; idx < 1024; idx += 512) {
    const int r = idx >> 6, c = idx & 63;
    S[r * 68 + c] = states[(r0g + r) * 64 + c];
  }
  {
    const int r = tid >> 5, c = tid & 31;
    Aa[r * 36 + c] = actions[(r0g + r) * 32 + c];
    Ap[r * 36 + c] = policies[(r0g + r) * 32 + c];
  }
  st128<512>(tid, ws + OFF_WSAPT, Bs, 64);
  __syncthreads();
  // common (state) part of Esap, K=64
  float cm[4] = {};
  g1(tid, S, 68, Bs, 64, cm);
  __syncthreads();
  st128<512>(tid, ws + OFF_WSAPT + 8192, Bs, 32);
  __syncthreads();
  // act/pol tails, K=32
  float aa[4] = {cm[0], cm[1], cm[2], cm[3]};
  float ap[4] = {cm[0], cm[1], cm[2], cm[3]};
  g2A(tid, Aa, Ap, 36, Bs, 32, aa, ap);
  epi<true, true>(tid, aa, Ea, 132, b_sap);
  epi<true, true>(tid, ap, Ep, 132, b_sap);
  __syncthreads();
  for (int idx = tid; idx < 2048; idx += 512) {
    const int r = idx >> 7, c = idx & 127;
    Ep[r * 132 + c] -= Ea[r * 132 + c];
  }
  __syncthreads();
  // av_act / delta (K=128 in 2 chunks)
  st128<512>(tid, ws + OFF_WAVT, Bs, 64);
  __syncthreads();
  float av[4] = {}, dl[4] = {};
  g2A(tid, Ea, Ep, 132, Bs, 64, av, dl);
  __syncthreads();
  st128<512>(tid, ws + OFF_WAVT + 8192, Bs, 64);
  __syncthreads();
  g2A(tid, Ea + 64, Ep + 64, 132, Bs, 64, av, dl);
  __syncthreads();  // all reads of Ea done before overwrite
  epi<false, false>(tid, av, Ea, 132, nullptr);  // Ea := AVs
  epi<false, false>(tid, dl, Dd, 132, nullptr);
  __syncthreads();
  // hd = delta @ Wf1^T ; ha = av_act @ Wf1^T (shared staging, [128][68] in one pass)
  st64r<512>(tid, ws + OFF_WF1T, Bs, 128);
  __syncthreads();
  float ah[2] = {}, aha[2] = {};
  gH2(tid, Dd, Ea, 132, Bs, 64, ah, aha);
  gH2(tid, Dd + 64, Ea + 64, 132, Bs + 64 * 68, 64, ah, aha);
  {
    const int c0 = (tid & 31) * 2, rg = tid >> 5;
    float2 vh; vh.x = ah[0]; vh.y = ah[1];
    float2 va; va.x = aha[0]; va.y = aha[1];
    *reinterpret_cast<float2*>(&ws[OFF_HD + (r0g + rg) * 64 + c0]) = vh;
    *reinterpret_cast<float2*>(&ws[OFF_HA + (r0g + rg) * 64 + c0]) = va;
  }
  __syncthreads();
  // e = lrelu(states @ Wpre^T + b) -> Er + ws.E
  st128<512>(tid, ws + OFF_WPRET, Bs, 64);
  __syncthreads();
  {
    float ae[4] = {};
    g1(tid, S, 68, Bs, 64, ae);
    const int c0 = (tid & 31) * 4, rg = tid >> 5;
    float t[4];
#pragma unroll
    for (int i = 0; i < 4; ++i) {
      float x = ae[i] + b_se_pre[c0 + i];
      t[i] = (x > 0.f) ? x : NSLOPE * x;
    }
    float4 v; v.x = t[0]; v.y = t[1]; v.z = t[2]; v.w = t[3];
    *reinterpret_cast<float4*>(&Er[rg * 132 + c0]) = v;
    *reinterpret_cast<float4*>(&ws[OFF_E + (r0g + rg) * 128 + c0]) = v;
  }
  __syncthreads();
  wrT(tid, Er, ws + OFF_ET + b * 8192, rq);
  st128<512>(tid, ws + OFF_M, Bs, 64);
  __syncthreads();
  // f = e @ M (K=128) -> ws.Q
  float af[4] = {};
  g1(tid, Er, 132, Bs, 64, af);
  __syncthreads();
  st128<512>(tid, ws + OFF_M + 8192, Bs, 64);
  __syncthreads();
  g1(tid, Er + 64, 132, Bs, 64, af);
  epi<false, false>(tid, af, ws + OFF_Q + r0g * 128, 128, nullptr);
}

// P3: grid 256 (swizzled), 512 thr, 16 rows. score1 -> w_pre ; av_pre ; se ; f2.
__global__ __launch_bounds__(512) void P3(const float* __restrict__ b_se,
                                          float* __restrict__ ws,
                                          float* __restrict__ out) {
  __shared__ float Qs[16 * 132];
  __shared__ float Bs[8704];
  __shared__ float Wp[16 * 68], AV[16 * 132], SEr[16 * 132];
  const int tid = threadIdx.x;
  const int wid = ((blockIdx.x & 7) << 5) | (blockIdx.x >> 3);
  const int b = wid >> 2, rq = wid & 3;
  const int r0g = b * 64 + rq * 16;

  {
    const int r = tid >> 5, c = tid & 31;
    *reinterpret_cast<float4*>(&Qs[r * 132 + c * 4]) =
        *reinterpret_cast<const float4*>(&ws[OFF_Q + (r0g + r) * 128 + c * 4]);
  }
  st64r<512>(tid, ws + OFF_ET + b * 8192, Bs, 128);
  __syncthreads();
  float sc[2] = {};
  score_full(tid, Qs, Bs, sc);
  softmax_write(tid, sc, Wp, out + BNN + b * 4096 + rq * 1024);
  __syncthreads();
  // av_pre = w_pre @ e[b] (K=64)
  st128<512>(tid, ws + OFF_E + b * 8192, Bs, 64);
  __syncthreads();
  {
    float a[4] = {};
    g1(tid, Wp, 68, Bs, 64, a);
    epi<false, false>(tid, a, AV, 132, nullptr);
  }
  __syncthreads();
  // se = lrelu(av_pre @ Wse^T + b_se) (K=128)
  st128<512>(tid, ws + OFF_WSET, Bs, 64);
  __syncthreads();
  float as[4] = {};
  g1(tid, AV, 132, Bs, 64, as);
  __syncthreads();
  st128<512>(tid, ws + OFF_WSET + 8192, Bs, 64);
  __syncthreads();
  g1(tid, AV + 64, 132, Bs, 64, as);
  {
    const int c0 = (tid & 31) * 4, rg = tid >> 5;
    float t[4];
#pragma unroll
    for (int i = 0; i < 4; ++i) {
      float x = as[i] + b_se[c0 + i];
      t[i] = (x > 0.f) ? x : NSLOPE * x;
    }
    float4 v; v.x = t[0]; v.y = t[1]; v.z = t[2]; v.w = t[3];
    *reinterpret_cast<float4*>(&SEr[rg * 132 + c0]) = v;
  }
  __syncthreads();
  wrT(tid, SEr, ws + OFF_SET + b * 8192, rq);
  st128<512>(tid, ws + OFF_M, Bs, 64);
  __syncthreads();
  // f2 = se @ M (K=128) -> ws.Q
  float af[4] = {};
  g1(tid, SEr, 132, Bs, 64, af);
  __syncthreads();
  st128<512>(tid, ws + OFF_M + 8192, Bs, 64);
  __syncthreads();
  g1(tid, SEr + 64, 132, Bs, 64, af);
  epi<false, false>(tid, af, ws + OFF_Q + r0g * 128, 128, nullptr);
}

// P4: grid 256 (swizzled), 512 thr, 16 rows. score2 -> w ; h_base = w @ ha ; head.
__global__ __launch_bounds__(512) void P4(const float* __restrict__ Wf2g,
                                          float* __restrict__ ws,
                                          float* __restrict__ out) {
  __shared__ float Qs[16 * 132];
  __shared__ float Bs[8704];
  __shared__ float Wp[16 * 68], Hb[16 * 66];
  __shared__ float Hd[64 * 69];
  __shared__ float Wf2s[64];
  const int tid = threadIdx.x;
  const int wid = ((blockIdx.x & 7) << 5) | (blockIdx.x >> 3);
  const int b = wid >> 2, rq = wid & 3;
  const int r0g = b * 64 + rq * 16;

  for (int idx = tid; idx < 4096; idx += 512)
    Hd[(idx >> 6) * 69 + (idx & 63)] = ws[OFF_HD + b * 4096 + idx];
  if (tid < 64) Wf2s[tid] = Wf2g[tid];
  {
    const int r = tid >> 5, c = tid & 31;
    *reinterpret_cast<float4*>(&Qs[r * 132 + c * 4]) =
        *reinterpret_cast<const float4*>(&ws[OFF_Q + (r0g + r) * 128 + c * 4]);
  }
  st64r<512>(tid, ws + OFF_SET + b * 8192, Bs, 128);
  __syncthreads();
  float sc[2] = {};
  score_full(tid, Qs, Bs, sc);
  softmax_write(tid, sc, Wp, out + 2 * BNN + b * 4096 + rq * 1024);
  __syncthreads();
  // h_base = w @ ha[b] (K=64)
  st64r<512>(tid, ws + OFF_HA + b * 4096, Bs, 64);
  __syncthreads();
  float ah[2] = {};
  gH(tid, Wp, 68, Bs, 64, ah);
  {
    const int c0 = (tid & 31) * 2, rg = tid >> 5;
    float2 v; v.x = ah[0]; v.y = ah[1];
    *reinterpret_cast<float2*>(&Hb[rg * 66 + c0]) = v;
  }
  __syncthreads();
  // head: value[i][j] = sum_f lrelu(Hb[i,f] + w[i,j]*Hd[j,f]) * Wf2[f]
  const int j = tid & 63, iw = tid >> 6;
  float wv[2], a2[2] = {0.f, 0.f};
#pragma unroll
  for (int r = 0; r < 2; ++r) wv[r] = Wp[(iw * 2 + r) * 68 + j];
  for (int f = 0; f < 64; ++f) {
    const float hdv = Hd[j * 69 + f];
    const float wf = Wf2s[f];
#pragma unroll
    for (int r = 0; r < 2; ++r) {
      float t = Hb[(iw * 2 + r) * 66 + f] + wv[r] * hdv;
      t = (t > 0.f) ? t : NSLOPE * t;
      a2[r] += t * wf;
    }
  }
#pragma unroll
  for (int r = 0; r < 2; ++r)
    out[(r0g + iw * 2 + r) * 64 + j] = a2[r];
}

extern "C" void kernel_launch(void* const* d_in, const int* in_sizes, int n_in,
                              void* d_out, int out_size, void* d_ws, size_t ws_size,
                              hipStream_t stream) {
  const float* states   = (const float*)d_in[0];
  const float* policies = (const float*)d_in[1];
  const float* actions  = (const float*)d_in[2];
  const float* W_se_pre = (const float*)d_in[3];
  const float* b_se_pre = (const float*)d_in[4];
  const float* W_key    = (const float*)d_in[5];
  const float* W_query  = (const float*)d_in[6];
  const float* W_se     = (const float*)d_in[7];
  const float* b_se     = (const float*)d_in[8];
  const float* W_sap    = (const float*)d_in[9];
  const float* b_sap    = (const float*)d_in[10];
  const float* W_av     = (const float*)d_in[11];
  const float* W_f1     = (const float*)d_in[12];
  const float* W_f2     = (const float*)d_in[13];
  float* out = (float*)d_out;
  float* ws  = (float*)d_ws;

  WPREP<<<dim3(128), dim3(512), 0, stream>>>(
      W_se_pre, W_query, W_key, W_se, W_sap, W_av, W_f1, ws);
  P1<<<dim3(256), dim3(512), 0, stream>>>(states, policies, actions, b_sap, b_se_pre, ws);
  P3<<<dim3(256), dim3(512), 0, stream>>>(b_se, ws, out);
  P4<<<dim3(256), dim3(512), 0, stream>>>(W_f2, ws, out);
}